// Round 1
// baseline (519.231 us; speedup 1.0000x reference)
//
#include <hip/hip_runtime.h>
#include <math.h>

#define EPS 1e-8f
constexpr int B = 64, N = 1024, W = 128;

// Kernel 1: per memory row (b,n): copy row to out_mem, compute
// sim[b,n] = beta[b] * dot(m_hat, k_hat). One 64-lane wave per row,
// 4 rows per 256-thread block. float2 per lane (128 floats/row).
__global__ __launch_bounds__(256) void sim_memcopy_kernel(
    const float* __restrict__ w_key, const float* __restrict__ w_beta,
    const float* __restrict__ memory, float* __restrict__ out_mem,
    float* __restrict__ sim_out)
{
    const int wave = threadIdx.x >> 6;
    const int lane = threadIdx.x & 63;
    const int r = blockIdx.x * 4 + wave;      // row in [0, B*N)
    const int b = r >> 10;                    // N = 1024
    const size_t moff = (size_t)r * W + lane * 2;

    const float2 mv = *reinterpret_cast<const float2*>(memory + moff);
    const float2 kv = *reinterpret_cast<const float2*>(w_key + b * W + lane * 2);
    *reinterpret_cast<float2*>(out_mem + moff) = mv;

    float dot = mv.x * kv.x + mv.y * kv.y;
    float msq = mv.x * mv.x + mv.y * mv.y;
    float ksq = kv.x * kv.x + kv.y * kv.y;
    #pragma unroll
    for (int off = 32; off; off >>= 1) {
        dot += __shfl_xor(dot, off);
        msq += __shfl_xor(msq, off);
        ksq += __shfl_xor(ksq, off);
    }
    if (lane == 0) {
        const float beta = 1.0f + log1pf(expf(w_beta[b]));
        const float sim = dot / ((sqrtf(msq) + EPS) * (sqrtf(ksq) + EPS));
        sim_out[r] = sim * beta;
    }
}

// Kernel 2: per batch b: softmax over n, gates, w_weights, precedence_new.
// 64 blocks x 1024 threads (one thread per n).
__global__ __launch_bounds__(1024) void weights_kernel(
    const float* __restrict__ sim, const float* __restrict__ a_gate,
    const float* __restrict__ w_gate, const float* __restrict__ alloc,
    const float* __restrict__ prec, float* __restrict__ out_w,
    float* __restrict__ out_prec)
{
    const int b = blockIdx.x;
    const int n = threadIdx.x;
    const int wave = n >> 6, lane = n & 63;
    __shared__ float red[16];

    const float s = sim[b * N + n];

    // block max
    float m = s;
    #pragma unroll
    for (int off = 32; off; off >>= 1) m = fmaxf(m, __shfl_xor(m, off));
    if (lane == 0) red[wave] = m;
    __syncthreads();
    m = red[0];
    #pragma unroll
    for (int i = 1; i < 16; i++) m = fmaxf(m, red[i]);
    __syncthreads();

    // block sum of exp
    const float e = expf(s - m);
    float sum = e;
    #pragma unroll
    for (int off = 32; off; off >>= 1) sum += __shfl_xor(sum, off);
    if (lane == 0) red[wave] = sum;
    __syncthreads();
    sum = 0.0f;
    #pragma unroll
    for (int i = 0; i < 16; i++) sum += red[i];
    __syncthreads();

    const float c  = e / sum;
    const float ag = 1.0f / (1.0f + expf(-a_gate[b]));
    const float wg = 1.0f / (1.0f + expf(-w_gate[b]));
    const float w  = wg * (ag * alloc[b * N + n] + (1.0f - ag) * c);
    out_w[b * N + n] = w;

    // block sum of w for precedence update
    float wsum = w;
    #pragma unroll
    for (int off = 32; off; off >>= 1) wsum += __shfl_xor(wsum, off);
    if (lane == 0) red[wave] = wsum;
    __syncthreads();
    wsum = 0.0f;
    #pragma unroll
    for (int i = 0; i < 16; i++) wsum += red[i];

    out_prec[b * N + n] = (1.0f - wsum) * prec[b * N + n] + w;
}

// Kernel 3: link update. One block per (b,i) row; float4 per thread.
// link[b,i,j] = (1 - w_i - w_j)*L[b,i,j] + w_i*p_j ; diagonal zeroed.
__global__ __launch_bounds__(256) void link_kernel(
    const float* __restrict__ link_in, const float* __restrict__ w,
    const float* __restrict__ prec, float* __restrict__ out_link)
{
    const int r = blockIdx.x;     // b*N + i
    const int b = r >> 10;
    const int i = r & 1023;
    const float wi = w[r];
    const int j0 = threadIdx.x * 4;
    const size_t base = (size_t)r * N + j0;

    const float4 L  = *reinterpret_cast<const float4*>(link_in + base);
    const float4 wj = *reinterpret_cast<const float4*>(w + b * N + j0);
    const float4 pj = *reinterpret_cast<const float4*>(prec + b * N + j0);

    float4 o;
    o.x = (1.0f - wi - wj.x) * L.x + wi * pj.x;
    o.y = (1.0f - wi - wj.y) * L.y + wi * pj.y;
    o.z = (1.0f - wi - wj.z) * L.z + wi * pj.z;
    o.w = (1.0f - wi - wj.w) * L.w + wi * pj.w;

    const int d = i - j0;
    if (d >= 0 && d < 4) (&o.x)[d] = 0.0f;

    *reinterpret_cast<float4*>(out_link + base) = o;
}

extern "C" void kernel_launch(void* const* d_in, const int* in_sizes, int n_in,
                              void* d_out, int out_size, void* d_ws, size_t ws_size,
                              hipStream_t stream) {
    const float* w_key  = (const float*)d_in[0];
    const float* w_beta = (const float*)d_in[1];
    // d_in[2] = e_vector (unused), d_in[3] = w_vector (unused)
    const float* a_gate = (const float*)d_in[4];
    const float* w_gate = (const float*)d_in[5];
    const float* alloc  = (const float*)d_in[6];
    const float* memory = (const float*)d_in[7];
    const float* linkm  = (const float*)d_in[8];
    const float* prec   = (const float*)d_in[9];

    float* out      = (float*)d_out;
    float* out_w    = out;                              // B*N
    float* out_mem  = out_w + (size_t)B * N;            // B*N*W
    float* out_link = out_mem + (size_t)B * N * W;      // B*N*N
    float* out_prec = out_link + (size_t)B * N * N;     // B*N

    float* sim = (float*)d_ws;                          // B*N floats

    sim_memcopy_kernel<<<B * N / 4, 256, 0, stream>>>(w_key, w_beta, memory, out_mem, sim);
    weights_kernel<<<B, 1024, 0, stream>>>(sim, a_gate, w_gate, alloc, prec, out_w, out_prec);
    link_kernel<<<B * N, 256, 0, stream>>>(linkm, out_w, prec, out_link);
}

// Round 3
// 507.911 us; speedup vs baseline: 1.0223x; 1.0223x over previous
//
#include <hip/hip_runtime.h>
#include <math.h>

#define EPS 1e-8f
constexpr int B = 64, N = 1024, W = 128;

// Kernel 1: per memory row (b,n): copy row to out_mem, compute
// sim[b,n] = beta[b] * cos(m, k). One 32-lane half-wave per row (float4 =
// 512B/row), 8 rows per 256-thread block.
__global__ __launch_bounds__(256) void sim_memcopy_kernel(
    const float* __restrict__ w_key, const float* __restrict__ w_beta,
    const float* __restrict__ memory, float* __restrict__ out_mem,
    float* __restrict__ sim_out)
{
    const int half = threadIdx.x >> 5;        // 0..7 (half-wave id)
    const int l    = threadIdx.x & 31;
    const int r = blockIdx.x * 8 + half;      // row in [0, B*N); blocks never straddle b
    const int b = r >> 10;                    // N = 1024
    const size_t moff = (size_t)r * W + l * 4;

    const float4 mv = *reinterpret_cast<const float4*>(memory + moff);
    const float4 kv = *reinterpret_cast<const float4*>(w_key + b * W + l * 4);
    *reinterpret_cast<float4*>(out_mem + moff) = mv;

    float dot = mv.x * kv.x + mv.y * kv.y + mv.z * kv.z + mv.w * kv.w;
    float msq = mv.x * mv.x + mv.y * mv.y + mv.z * mv.z + mv.w * mv.w;
    float ksq = kv.x * kv.x + kv.y * kv.y + kv.z * kv.z + kv.w * kv.w;
    #pragma unroll
    for (int off = 16; off; off >>= 1) {   // stays within the 32-lane group
        dot += __shfl_xor(dot, off);
        msq += __shfl_xor(msq, off);
        ksq += __shfl_xor(ksq, off);
    }
    if (l == 0) {
        const float beta = 1.0f + log1pf(expf(w_beta[b]));
        const float sim = dot / ((sqrtf(msq) + EPS) * (sqrtf(ksq) + EPS));
        sim_out[r] = sim * beta;
    }
}

// Kernel 2: per batch b: softmax over n, gates, w_weights, precedence_new.
// 64 blocks x 1024 threads (one thread per n). KB-scale traffic.
__global__ __launch_bounds__(1024) void weights_kernel(
    const float* __restrict__ sim, const float* __restrict__ a_gate,
    const float* __restrict__ w_gate, const float* __restrict__ alloc,
    const float* __restrict__ prec, float* __restrict__ out_w,
    float* __restrict__ out_prec)
{
    const int b = blockIdx.x;
    const int n = threadIdx.x;
    const int wave = n >> 6, lane = n & 63;
    __shared__ float red[16];

    const float s = sim[b * N + n];

    // block max
    float m = s;
    #pragma unroll
    for (int off = 32; off; off >>= 1) m = fmaxf(m, __shfl_xor(m, off));
    if (lane == 0) red[wave] = m;
    __syncthreads();
    m = red[0];
    #pragma unroll
    for (int i = 1; i < 16; i++) m = fmaxf(m, red[i]);
    __syncthreads();

    // block sum of exp
    const float e = expf(s - m);
    float sum = e;
    #pragma unroll
    for (int off = 32; off; off >>= 1) sum += __shfl_xor(sum, off);
    if (lane == 0) red[wave] = sum;
    __syncthreads();
    sum = 0.0f;
    #pragma unroll
    for (int i = 0; i < 16; i++) sum += red[i];
    __syncthreads();

    const float c  = e / sum;
    const float ag = 1.0f / (1.0f + expf(-a_gate[b]));
    const float wg = 1.0f / (1.0f + expf(-w_gate[b]));
    const float w  = wg * (ag * alloc[b * N + n] + (1.0f - ag) * c);
    out_w[b * N + n] = w;

    // block sum of w for precedence update
    float wsum = w;
    #pragma unroll
    for (int off = 32; off; off >>= 1) wsum += __shfl_xor(wsum, off);
    if (lane == 0) red[wave] = wsum;
    __syncthreads();
    wsum = 0.0f;
    #pragma unroll
    for (int i = 0; i < 16; i++) wsum += red[i];

    out_prec[b * N + n] = (1.0f - wsum) * prec[b * N + n] + w;
}

// Kernel 3: link update, row-batched. One block handles TI=16 consecutive
// i-rows of one batch; each thread owns cols j0..j0+3 and reloads w_j/p_j
// ONCE, reusing them across the 16 rows (16 independent load->fma->store
// chains for memory-level parallelism).
// link[b,i,j] = (1 - w_i - w_j)*L[b,i,j] + w_i*p_j ; diagonal zeroed.
constexpr int TI = 16;
__global__ __launch_bounds__(256) void link_kernel(
    const float* __restrict__ link_in, const float* __restrict__ w,
    const float* __restrict__ prec, float* __restrict__ out_link)
{
    const int b  = blockIdx.x >> 6;           // N/TI = 64 row-tiles per batch
    const int i0 = (blockIdx.x & 63) * TI;
    const int j0 = threadIdx.x * 4;

    const float4 wj = *reinterpret_cast<const float4*>(w + b * N + j0);
    const float4 pj = *reinterpret_cast<const float4*>(prec + b * N + j0);

    const float* Lrow = link_in + ((size_t)b * N + i0) * N + j0;
    float*       Orow = out_link + ((size_t)b * N + i0) * N + j0;

    float wi[TI];
    #pragma unroll
    for (int t = 0; t < TI; t++) wi[t] = w[b * N + i0 + t];   // broadcast loads

    #pragma unroll
    for (int t = 0; t < TI; t++) {
        const int i = i0 + t;
        const float4 L = *reinterpret_cast<const float4*>(Lrow + (size_t)t * N);
        const float c0 = 1.0f - wi[t];
        float4 o;
        o.x = (c0 - wj.x) * L.x + wi[t] * pj.x;
        o.y = (c0 - wj.y) * L.y + wi[t] * pj.y;
        o.z = (c0 - wj.z) * L.z + wi[t] * pj.z;
        o.w = (c0 - wj.w) * L.w + wi[t] * pj.w;
        // zero the diagonal (static component index -> no scratch)
        o.x = (i == j0    ) ? 0.0f : o.x;
        o.y = (i == j0 + 1) ? 0.0f : o.y;
        o.z = (i == j0 + 2) ? 0.0f : o.z;
        o.w = (i == j0 + 3) ? 0.0f : o.w;
        *reinterpret_cast<float4*>(Orow + (size_t)t * N) = o;
    }
}

extern "C" void kernel_launch(void* const* d_in, const int* in_sizes, int n_in,
                              void* d_out, int out_size, void* d_ws, size_t ws_size,
                              hipStream_t stream) {
    const float* w_key  = (const float*)d_in[0];
    const float* w_beta = (const float*)d_in[1];
    // d_in[2] = e_vector (unused), d_in[3] = w_vector (unused)
    const float* a_gate = (const float*)d_in[4];
    const float* w_gate = (const float*)d_in[5];
    const float* alloc  = (const float*)d_in[6];
    const float* memory = (const float*)d_in[7];
    const float* linkm  = (const float*)d_in[8];
    const float* prec   = (const float*)d_in[9];

    float* out      = (float*)d_out;
    float* out_w    = out;                              // B*N
    float* out_mem  = out_w + (size_t)B * N;            // B*N*W
    float* out_link = out_mem + (size_t)B * N * W;      // B*N*N
    float* out_prec = out_link + (size_t)B * N * N;     // B*N

    float* sim = (float*)d_ws;                          // B*N floats

    sim_memcopy_kernel<<<B * N / 8, 256, 0, stream>>>(w_key, w_beta, memory, out_mem, sim);
    weights_kernel<<<B, 1024, 0, stream>>>(sim, a_gate, w_gate, alloc, prec, out_w, out_prec);
    link_kernel<<<B * (N / TI), 256, 0, stream>>>(linkm, out_w, prec, out_link);
}